// Round 1
// baseline (155.456 us; speedup 1.0000x reference)
//
#include <hip/hip_runtime.h>
#include <hip/hip_cooperative_groups.h>

namespace cg = cooperative_groups;

#define NN 64
#define CC 128
#define TT 2048
#define SS 9
#define PAD 4
#define EPSF 1e-5f
#define TL 32                 // t columns per tile
#define ROWS (CC + 2 * PAD)   // 136 staged rows
#define STRIDE (TL + 1)       // 33: odd -> conflict-free c-per-lane reads
#define NB 16                 // stat buckets

// ---------------------------------------------------------------------------
// Fused cooperative kernel: conv+stats (2 tiles/block, results in registers)
//  -> grid sync -> fold stats -> normalize in regs -> LDS transpose -> store.
// Eliminates the 128 MB raw-conv HBM round trip of the two-kernel version.
// 2048 blocks x 256 thr, 8 blocks/CU (LDS 17952 B, VGPR capped at 64).
// ---------------------------------------------------------------------------
__global__ __launch_bounds__(256, 8) void fused_all(
    const float* __restrict__ x, const float* __restrict__ cw,
    float* __restrict__ buckets, const float* __restrict__ gamma,
    const float* __restrict__ beta, float* __restrict__ out)
{
    __shared__ float ls[ROWS * STRIDE];   // 17952 B only -> 8 blocks/CU

    const int n     = blockIdx.y;
    const int t0    = blockIdx.x * (2 * TL);
    const int tid   = threadIdx.x;
    const int lane  = tid & 63;
    const int wid   = tid >> 6;
    const int col   = lane & 31;
    const int rhalf = lane >> 5;          // two 32-lane rows per wave instr
    const float* __restrict__ xn = x + (size_t)n * CC * TT;

    const int c  = tid & (CC - 1);        // fixed output channel per thread
    const int jb = (tid >> 7) * (TL / 2); // 0 or 16
    float wv[SS];
#pragma unroll
    for (int s = 0; s < SS; ++s) wv[s] = cw[c * SS + s];

    float res[2 * (TL / 2)];              // 32 conv outputs held across sync
    float s1 = 0.f, s2 = 0.f;

#pragma unroll
    for (int half = 0; half < 2; ++half) {
        const int tb = t0 + half * TL;

        // ---- stage: ls[c2+4][j] = xs[n, c2, tb+j] (pre-shifted, padded) ----
#pragma unroll
        for (int i = 0; i < 17; ++i) {    // 34 rows per wave, 2 per iter
            const int r  = wid * 34 + 2 * i + rhalf;
            const int c2 = r - PAD;
            float v = 0.f;
            if (c2 >= 0 && c2 < CC) {
                const int sh = (c2 % SS) - PAD;
                const int t  = tb + col - sh;
                if (t >= 0 && t < TT) v = xn[c2 * TT + t];
            }
            ls[r * STRIDE + col] = v;
        }
        __syncthreads();

        // ---- conv: rows c..c+8, conflict-free (STRIDE odd, c = lane) ----
        const int base = c * STRIDE + jb;
#pragma unroll
        for (int j = 0; j < TL / 2; ++j) {
            float acc = 0.f;
#pragma unroll
            for (int s = 0; s < SS; ++s)
                acc = fmaf(wv[s], ls[base + s * STRIDE + j], acc);
            res[half * (TL / 2) + j] = acc;
            s1 += acc;
            s2 = fmaf(acc, acc, s2);
        }
        __syncthreads();                  // conv reads done; ls reusable
    }

    // ---- bucketed stat atomics (distinct addr per lane; low contention) ----
    float* bs = buckets + ((blockIdx.x + blockIdx.y) & (NB - 1)) * 2 * CC;
    atomicAdd(&bs[c],      s1);
    atomicAdd(&bs[CC + c], s2);

    cg::this_grid().sync();               // all stats visible device-wide

    // ---- fold 16 buckets (L2-resident 16 KB) -> per-channel g,b in LDS ----
    if (tid < CC) {
        float t1 = 0.f, t2 = 0.f;
#pragma unroll
        for (int k = 0; k < NB; ++k) {
            t1 += buckets[k * 2 * CC + tid];
            t2 += buckets[k * 2 * CC + CC + tid];
        }
        const float inv_cnt = 1.0f / (float)(NN * TT);
        const float mean = t1 * inv_cnt;
        const float var  = t2 * inv_cnt - mean * mean;
        const float inv  = rsqrtf(var + EPSF);
        const float gg   = gamma[tid] * inv;
        ls[tid]      = gg;
        ls[CC + tid] = beta[tid] - mean * gg;
    }
    __syncthreads();
    const float g = ls[c];
    const float b = ls[CC + c];
    __syncthreads();                      // reads done before transpose reuse

    // ---- normalize in regs -> LDS transpose -> coalesced store ----
#pragma unroll
    for (int half = 0; half < 2; ++half) {
#pragma unroll
        for (int j = 0; j < TL / 2; ++j) {
            float v = fmaf(res[half * (TL / 2) + j], g, b);
            ls[c * STRIDE + jb + j] = v > 0.f ? v : 0.f;
        }
        __syncthreads();
        float* __restrict__ on = out + (size_t)n * CC * TT + t0 + half * TL;
#pragma unroll
        for (int i = 0; i < 16; ++i) {    // 32 rows per wave, 2 per iter
            const int r = wid * 32 + 2 * i + rhalf;
            on[(size_t)r * TT + col] = ls[r * STRIDE + col];
        }
        __syncthreads();
    }
}

// ---------------------------------------------------------------------------
// Fallback path (verified two-kernel version) — used only if the driver
// reports < 8 resident blocks/CU for the cooperative kernel.
// ---------------------------------------------------------------------------
__global__ __launch_bounds__(256, 8) void conv_store_stats(
    const float* __restrict__ x, const float* __restrict__ cw,
    float* __restrict__ buckets, float* __restrict__ out)
{
    __shared__ float ls[ROWS * STRIDE];
    __shared__ float sred[512];

    const int n     = blockIdx.y;
    const int t0    = blockIdx.x * TL;
    const int tid   = threadIdx.x;
    const int lane  = tid & 63;
    const int wid   = tid >> 6;
    const int col   = lane & 31;
    const int rhalf = lane >> 5;
    const float* __restrict__ xn = x + (size_t)n * CC * TT;

#pragma unroll
    for (int i = 0; i < 17; ++i) {
        const int r  = wid * 34 + 2 * i + rhalf;
        const int c2 = r - PAD;
        float v = 0.f;
        if (c2 >= 0 && c2 < CC) {
            const int sh = (c2 % SS) - PAD;
            const int t  = t0 + col - sh;
            if (t >= 0 && t < TT) v = xn[c2 * TT + t];
        }
        ls[r * STRIDE + col] = v;
    }

    const int c  = tid & (CC - 1);
    const int jb = (tid >> 7) * (TL / 2);
    float wv[SS];
#pragma unroll
    for (int s = 0; s < SS; ++s) wv[s] = cw[c * SS + s];

    __syncthreads();

    const int base = c * STRIDE + jb;
    float res[TL / 2];
    float s1 = 0.f, s2 = 0.f;
#pragma unroll
    for (int j = 0; j < TL / 2; ++j) {
        float acc = 0.f;
#pragma unroll
        for (int s = 0; s < SS; ++s)
            acc = fmaf(wv[s], ls[base + s * STRIDE + j], acc);
        res[j] = acc;
        s1 += acc;
        s2 = fmaf(acc, acc, s2);
    }

    __syncthreads();
#pragma unroll
    for (int j = 0; j < TL / 2; ++j)
        ls[c * STRIDE + jb + j] = res[j];
    sred[tid]       = s1;
    sred[256 + tid] = s2;
    __syncthreads();

    if (tid < CC) {
        float* bs = buckets + ((blockIdx.x + blockIdx.y) & (NB - 1)) * 2 * CC;
        atomicAdd(&bs[tid],      sred[tid]       + sred[tid + 128]);
        atomicAdd(&bs[CC + tid], sred[256 + tid] + sred[256 + tid + 128]);
    }

    float* __restrict__ on = out + (size_t)n * CC * TT + t0;
#pragma unroll
    for (int i = 0; i < 16; ++i) {
        const int r = wid * 32 + 2 * i + rhalf;
        on[(size_t)r * TT + col] = ls[r * STRIDE + col];
    }
}

__global__ __launch_bounds__(256, 8) void norm_relu(
    const float* __restrict__ buckets, const float* __restrict__ gamma,
    const float* __restrict__ beta, float* __restrict__ out)
{
    const int row = blockIdx.x;
    const int c   = row & (CC - 1);

    float t1 = 0.f, t2 = 0.f;
#pragma unroll
    for (int k = 0; k < NB; ++k) {
        t1 += buckets[k * 2 * CC + c];
        t2 += buckets[k * 2 * CC + CC + c];
    }
    const float inv_cnt = 1.0f / (float)(NN * TT);
    const float mean = t1 * inv_cnt;
    const float var  = t2 * inv_cnt - mean * mean;
    const float inv  = rsqrtf(var + EPSF);
    const float g = gamma[c] * inv;
    const float b = beta[c] - mean * g;

    float4* __restrict__ o4 = (float4*)(out + (size_t)row * TT);
#pragma unroll
    for (int k = 0; k < 2; ++k) {
        const int i = threadIdx.x + k * 256;
        float4 v = o4[i];
        v.x = fmaf(v.x, g, b); v.y = fmaf(v.y, g, b);
        v.z = fmaf(v.z, g, b); v.w = fmaf(v.w, g, b);
        v.x = v.x > 0.f ? v.x : 0.f;
        v.y = v.y > 0.f ? v.y : 0.f;
        v.z = v.z > 0.f ? v.z : 0.f;
        v.w = v.w > 0.f ? v.w : 0.f;
        o4[i] = v;
    }
}

extern "C" void kernel_launch(void* const* d_in, const int* in_sizes, int n_in,
                              void* d_out, int out_size, void* d_ws, size_t ws_size,
                              hipStream_t stream)
{
    const float* x     = (const float*)d_in[0];
    const float* cw    = (const float*)d_in[1];
    const float* gamma = (const float*)d_in[2];
    const float* beta  = (const float*)d_in[3];
    float* out     = (float*)d_out;
    float* buckets = (float*)d_ws;        // [NB][2][CC]

    // One-time co-residency check (host-only query; graph-capture safe).
    static int coop_ok = -1;
    if (coop_ok < 0) {
        int nb = 0;
        hipError_t e = hipOccupancyMaxActiveBlocksPerMultiprocessor(
            &nb, fused_all, 256, 0);
        int dev = 0;
        hipGetDevice(&dev);
        hipDeviceProp_t prop;
        hipGetDeviceProperties(&prop, dev);
        const int need = (TT / (2 * TL)) * NN;   // 2048 blocks
        coop_ok = (e == hipSuccess &&
                   (long)nb * prop.multiProcessorCount >= need) ? 1 : 0;
    }

    hipMemsetAsync(buckets, 0, (size_t)NB * 2 * CC * sizeof(float), stream);

    if (coop_ok) {
        dim3 grid(TT / (2 * TL), NN);     // 32 x 64 = 2048 blocks (exact fit)
        void* kargs[] = { (void*)&x, (void*)&cw, (void*)&buckets,
                          (void*)&gamma, (void*)&beta, (void*)&out };
        hipLaunchCooperativeKernel(fused_all, grid, dim3(256), kargs, 0, stream);
    } else {
        dim3 grid1(TT / TL, NN);          // 64 x 64 = 4096 blocks
        conv_store_stats<<<grid1, 256, 0, stream>>>(x, cw, buckets, out);
        norm_relu<<<NN * CC, 256, 0, stream>>>(buckets, gamma, beta, out);
    }
}